// Round 2
// baseline (247.281 us; speedup 1.0000x reference)
//
#include <hip/hip_runtime.h>
#include <hip/hip_bf16.h>

// B=64, M=16, T=2048, L=64, K=32, N=1985
#define B_ 64
#define M_ 16
#define T_ 2048
#define L_ 64
#define K_ 32
#define N_ (T_ - L_ + 1)   // 1985
#define TN 64              // n-positions per block
#define NTH 256            // 4 waves: wave w owns n-subtile [16w,16w+16), both k-tiles
#define XROW 144           // per-plane row elems; need j<=123. 144 elems = 72 dw
                           // == 8 (mod 32) -> planes at bank offsets {0,8,16,24}:
                           // uniform 4 touches/bank = the 512B/wave floor.
#define STSTR 72           // st row stride elems (16B-aligned b128 reads, no 16-way bank hit)

typedef __attribute__((ext_vector_type(8))) short bf16x8;
typedef __attribute__((ext_vector_type(4))) float f32x4;

__device__ __forceinline__ unsigned short f2bf(float f) {
    __hip_bfloat16 h = __float2bfloat16(f);
    return __builtin_bit_cast(unsigned short, h);
}

__device__ __forceinline__ float elu_pen(float p) {
    // elu(-p) + 2
    return (p < 0.f) ? (2.f - p) : (__expf(-p) + 1.f);
}

// LDS: 18432 + 4608 + 4096 + 128 = 27264 B; 27264*6 = 163584 <= 163840 -> 6 blocks/CU.
// __launch_bounds__(256, 6): 6 waves/EU -> 6 blocks/CU resident, VGPR cap 85.
__global__ __launch_bounds__(NTH, 6)
void shapelet_mfma_kernel(const float* __restrict__ x,
                          const float* __restrict__ shp,
                          const float* __restrict__ pmap,
                          unsigned* __restrict__ out) {
    __shared__ __align__(16) unsigned short xbuf4[M_][4][XROW]; // 4 shifted bf16 planes
    __shared__ __align__(16) unsigned short st[K_][STSTR];      // shapelets bf16
    __shared__ __align__(16) float sqw[M_][TN];                 // fp32 sliding sum x^2
    __shared__ float ssb[K_];                                   // fp32 sum shp^2

    const int tid = threadIdx.x;
    const int n0 = blockIdx.x * TN;
    const int b  = blockIdx.y;
    const bool fast = (n0 + 2 * TN <= T_);   // false only for last tile (n0=1984)

    // ---- shapelets bf16 + ss fp32 (inline; no precompute kernel) ----
    for (int i = tid; i < K_ * 16; i += NTH) {
        const int k = i >> 4, l4 = (i & 15) * 4;
        float4 v = *(const float4*)(shp + k * L_ + l4);
        ushort4 sv = { f2bf(v.x), f2bf(v.y), f2bf(v.z), f2bf(v.w) };
        *(ushort4*)&st[k][l4] = sv;
    }
    if (tid < K_) {
        float s = 0.f;
        for (int l = 0; l < L_; ++l) { float v = shp[tid * L_ + l]; s = fmaf(v, v, s); }
        ssb[tid] = s;
    }

    // ---- stage x as 4 shifted bf16 planes: j4 = 0..120 -> j coverage 0..123 ----
    const float* xb = x + ((size_t)b * M_) * T_ + n0;
    for (int g = tid; g < M_ * 31; g += NTH) {
        const int m = g / 31, j4 = (g - m * 31) * 4;     // j4 in {0,4,...,120}
        const float* src = xb + m * T_ + j4;
        float h[8];
        if (fast) {
            float4 v0 = *(const float4*)src;
            float4 v1 = *(const float4*)(src + 4);
            h[0] = v0.x; h[1] = v0.y; h[2] = v0.z; h[3] = v0.w;
            h[4] = v1.x; h[5] = v1.y; h[6] = v1.z; h[7] = v1.w;
        } else {
#pragma unroll
            for (int i = 0; i < 8; ++i)
                h[i] = (n0 + j4 + i < T_) ? src[i] : 0.f;
        }
        unsigned short hb[8];
#pragma unroll
        for (int i = 0; i < 8; ++i) hb[i] = f2bf(h[i]);
#pragma unroll
        for (int s = 0; s < 4; ++s) {
            ushort4 sv = { hb[s], hb[s + 1], hb[s + 2], hb[s + 3] };
            *(ushort4*)&xbuf4[m][s][j4] = sv;
        }
    }
    // ---- sqw fp32 sliding window: 8 threads per m, 8 n each (threads 0..127) ----
    if (tid < M_ * 8) {
        const int m = tid >> 3, j0 = (tid & 7) * 8;
        const float* xr = x + ((size_t)b * M_ + m) * T_ + n0;
        float s = 0.f;
        if (fast) {
#pragma unroll
            for (int qd = 0; qd < 16; ++qd) {
                float4 v = *(const float4*)(xr + j0 + qd * 4);
                s = fmaf(v.x, v.x, s); s = fmaf(v.y, v.y, s);
                s = fmaf(v.z, v.z, s); s = fmaf(v.w, v.w, s);
            }
            sqw[m][j0] = s;
#pragma unroll
            for (int d = 1; d < 8; ++d) {
                float a = xr[j0 + d + L_ - 1], r = xr[j0 + d - 1];
                s += a * a - r * r;
                sqw[m][j0 + d] = s;
            }
        } else {
            for (int l = 0; l < L_; ++l) {
                float v = (n0 + j0 + l < T_) ? xr[j0 + l] : 0.f;
                s = fmaf(v, v, s);
            }
            sqw[m][j0] = s;
            for (int d = 1; d < 8; ++d) {
                float a = (n0 + j0 + d + L_ - 1 < T_) ? xr[j0 + d + L_ - 1] : 0.f;
                float r = (n0 + j0 + d - 1 < T_) ? xr[j0 + d - 1] : 0.f;
                s += a * a - r * r;
                sqw[m][j0 + d] = s;
            }
        }
    }
    __syncthreads();

    // ---- per-lane MFMA coordinates (proven layout) ----
    const int lane = tid & 63;
    const int w  = tid >> 6;       // wave -> n-subtile [16w, 16w+16)
    const int rl = lane & 15;      // A-row (n within subtile) / B-col (k within tile)
    const int q  = lane >> 4;      // quad
    const int sp = rl & 3;                          // shift plane
    const int e0 = 16 * w + 8 * q + (rl & ~3);      // 4-aligned elem base (max 84)
    const int eq = e0 >> 2;                         // uint2 index (max 21; +9 fits)
    const int nrow = n0 + 16 * w + 4 * q;           // lane's 4 output rows: nrow + reg

    // b_frags (registers, whole kernel): st[16t+rl][8q+32h .. +7]
    bf16x8 bfr[2][2];
#pragma unroll
    for (int t = 0; t < 2; ++t)
#pragma unroll
        for (int h = 0; h < 2; ++h)
            bfr[t][h] = *(const bf16x8*)&st[16 * t + rl][8 * q + 32 * h];

    const float ssk0 = ssb[rl], ssk1 = ssb[16 + rl];

    const float* pr0 = pmap + (size_t)rl * (M_ * N_) + nrow;   // k = rl
    const float* pr1 = pr0 + (size_t)16 * M_ * N_;             // k = rl + 16

    f32x4 wd0 = (f32x4)0.f, wd1 = (f32x4)0.f;
    const f32x4 zero = (f32x4)0.f;

    if (fast) {
        // Full unroll: all 32 pen loads are independent, compile-time addressed.
        // Under the 85-VGPR launch_bounds cap the scheduler keeps many in flight,
        // amortizing the ~200cy L2-hit latency (the round-0/1 bottleneck).
#pragma unroll
        for (int m = 0; m < M_; ++m) {
            float4 pm0 = *(const float4*)(pr0 + (size_t)m * N_);
            float4 pm1 = *(const float4*)(pr1 + (size_t)m * N_);

            const uint2* prow = (const uint2*)&xbuf4[m][sp][0];
            uint2 lo0 = prow[eq],     hi0 = prow[eq + 1];
            uint2 lo1 = prow[eq + 8], hi1 = prow[eq + 9];
            union { uint2 u2[2]; bf16x8 v; } fa0, fa1;
            fa0.u2[0] = lo0; fa0.u2[1] = hi0;
            fa1.u2[0] = lo1; fa1.u2[1] = hi1;

            f32x4 c0_ = __builtin_amdgcn_mfma_f32_16x16x32_bf16(fa0.v, bfr[0][0], zero, 0, 0, 0);
            c0_       = __builtin_amdgcn_mfma_f32_16x16x32_bf16(fa1.v, bfr[0][1], c0_, 0, 0, 0);
            f32x4 c1_ = __builtin_amdgcn_mfma_f32_16x16x32_bf16(fa0.v, bfr[1][0], zero, 0, 0, 0);
            c1_       = __builtin_amdgcn_mfma_f32_16x16x32_bf16(fa1.v, bfr[1][1], c1_, 0, 0, 0);

            const float pv0[4] = { pm0.x, pm0.y, pm0.z, pm0.w };
            const float pv1[4] = { pm1.x, pm1.y, pm1.z, pm1.w };
            f32x4 sq = *(const f32x4*)&sqw[m][16 * w + 4 * q];
#pragma unroll
            for (int r = 0; r < 4; ++r) {
                float pe0 = elu_pen(pv0[r]);
                float pe1 = elu_pen(pv1[r]);
                float u0 = fmaf(-2.f, c0_[r], sq[r] + ssk0);
                wd0[r] = fmaf(pe0, u0, wd0[r]);
                float u1 = fmaf(-2.f, c1_[r], sq[r] + ssk1);
                wd1[r] = fmaf(pe1, u1, wd1[r]);
            }
        }
    } else {
        // last n-tile only (32 of 2048 blocks): per-element guarded
#pragma unroll 2
        for (int m = 0; m < M_; ++m) {
            float4 pm0 = make_float4(0.f, 0.f, 0.f, 0.f);
            float4 pm1 = make_float4(0.f, 0.f, 0.f, 0.f);
            const float* r0_ = pr0 + (size_t)m * N_;
            const float* r1_ = pr1 + (size_t)m * N_;
            if (nrow     < N_) { pm0.x = r0_[0]; pm1.x = r1_[0]; }
            if (nrow + 1 < N_) { pm0.y = r0_[1]; pm1.y = r1_[1]; }
            if (nrow + 2 < N_) { pm0.z = r0_[2]; pm1.z = r1_[2]; }
            if (nrow + 3 < N_) { pm0.w = r0_[3]; pm1.w = r1_[3]; }

            const uint2* prow = (const uint2*)&xbuf4[m][sp][0];
            uint2 lo0 = prow[eq],     hi0 = prow[eq + 1];
            uint2 lo1 = prow[eq + 8], hi1 = prow[eq + 9];
            union { uint2 u2[2]; bf16x8 v; } fa0, fa1;
            fa0.u2[0] = lo0; fa0.u2[1] = hi0;
            fa1.u2[0] = lo1; fa1.u2[1] = hi1;

            f32x4 c0_ = __builtin_amdgcn_mfma_f32_16x16x32_bf16(fa0.v, bfr[0][0], zero, 0, 0, 0);
            c0_       = __builtin_amdgcn_mfma_f32_16x16x32_bf16(fa1.v, bfr[0][1], c0_, 0, 0, 0);
            f32x4 c1_ = __builtin_amdgcn_mfma_f32_16x16x32_bf16(fa0.v, bfr[1][0], zero, 0, 0, 0);
            c1_       = __builtin_amdgcn_mfma_f32_16x16x32_bf16(fa1.v, bfr[1][1], c1_, 0, 0, 0);

            const float pv0[4] = { pm0.x, pm0.y, pm0.z, pm0.w };
            const float pv1[4] = { pm1.x, pm1.y, pm1.z, pm1.w };
            f32x4 sq = *(const f32x4*)&sqw[m][16 * w + 4 * q];
#pragma unroll
            for (int r = 0; r < 4; ++r) {
                float pe0 = elu_pen(pv0[r]);
                float pe1 = elu_pen(pv1[r]);
                float u0 = fmaf(-2.f, c0_[r], sq[r] + ssk0);
                wd0[r] = fmaf(pe0, u0, wd0[r]);
                float u1 = fmaf(-2.f, c1_[r], sq[r] + ssk1);
                wd1[r] = fmaf(pe1, u1, wd1[r]);
            }
        }
    }

    // ---- min: 4 rows -> quads (shfl) -> LDS cross-wave -> 1 atomic per (b,k) ----
    __syncthreads();                       // sqw reads done; reuse as scratch
    float* red = (float*)&sqw[0][0];       // [4 waves][32]
#pragma unroll
    for (int t = 0; t < 2; ++t) {
        float lmin = __int_as_float(0x7F800000);
        const f32x4 wdv = t ? wd1 : wd0;
#pragma unroll
        for (int r = 0; r < 4; ++r)
            if (nrow + r < N_) lmin = fminf(lmin, wdv[r]);
        lmin = fminf(lmin, __shfl_xor(lmin, 16));
        lmin = fminf(lmin, __shfl_xor(lmin, 32));
        if (q == 0) red[w * 32 + t * 16 + rl] = lmin;
    }
    __syncthreads();
    if (tid < K_) {
        float v = fminf(fminf(red[tid], red[32 + tid]),
                        fminf(red[64 + tid], red[96 + tid]));
        atomicMin(out + (size_t)b * K_ + tid, __float_as_uint(fmaxf(v, 0.f)));
    }
}

extern "C" void kernel_launch(void* const* d_in, const int* in_sizes, int n_in,
                              void* d_out, int out_size, void* d_ws, size_t ws_size,
                              hipStream_t stream) {
    const float* x    = (const float*)d_in[0];   // (B, M, T)
    const float* shp  = (const float*)d_in[1];   // (K, L)
    const float* pmap = (const float*)d_in[2];   // (K, M, N)
    unsigned* out = (unsigned*)d_out;            // (B, K) float bits
    (void)d_ws; (void)ws_size;                   // no workspace: pen computed inline

    // out = 0xFFFFFFFF (> any non-negative float's bits) for atomicMin
    hipMemsetAsync(d_out, 0xFF, (size_t)B_ * K_ * sizeof(unsigned), stream);

    dim3 grid((N_ + TN - 1) / TN, B_);           // 32 x 64 = 2048 blocks, 8/CU, 6 resident
    shapelet_mfma_kernel<<<grid, dim3(NTH), 0, stream>>>(x, shp, pmap, out);
}

// Round 3
// 109.233 us; speedup vs baseline: 2.2638x; 2.2638x over previous
//
#include <hip/hip_runtime.h>
#include <hip/hip_bf16.h>

// B=64, M=16, T=2048, L=64, K=32, N=1985
#define B_ 64
#define M_ 16
#define T_ 2048
#define L_ 64
#define K_ 32
#define N_ (T_ - L_ + 1)   // 1985
#define TN 64              // n-positions per block
#define NTH 256            // 4 waves: wave w owns n-subtile [16w,16w+16), both k-tiles
#define XROW 144           // per-plane row elems; need j<=123. 144 elems = 72 dw
                           // == 8 (mod 32) -> planes at bank offsets {0,8,16,24}:
                           // uniform 4 touches/bank = the 512B/wave floor.
#define STSTR 72           // st row stride elems (16B-aligned b128 reads)

typedef __attribute__((ext_vector_type(8))) short bf16x8;
typedef __attribute__((ext_vector_type(4))) float f32x4;

__device__ __forceinline__ unsigned short f2bf(float f) {
    __hip_bfloat16 h = __float2bfloat16(f);
    return __builtin_bit_cast(unsigned short, h);
}

__device__ __forceinline__ float elu_pen(float p) {
    // elu(-p) + 2
    return (p < 0.f) ? (2.f - p) : (__expf(-p) + 1.f);
}

// LDS: 18432 + 4608 + 4096 + 128 = 27264 B; 27264*6 <= 163840 -> 6 blocks/CU.
// __launch_bounds__(256, 4): VGPR cap 128 — room for the depth-2 pen pipeline,
// NO full unroll (round-2's full unroll spilled 358 MB of scratch under cap 85).
__global__ __launch_bounds__(NTH, 4)
void shapelet_mfma_kernel(const float* __restrict__ x,
                          const float* __restrict__ shp,
                          const float* __restrict__ pmap,
                          unsigned* __restrict__ out) {
    __shared__ __align__(16) unsigned short xbuf4[M_][4][XROW]; // 4 shifted bf16 planes
    __shared__ __align__(16) unsigned short st[K_][STSTR];      // shapelets bf16
    __shared__ __align__(16) float sqw[M_][TN];                 // fp32 sliding sum x^2
    __shared__ float ssb[K_];                                   // fp32 sum shp^2

    const int tid = threadIdx.x;
    const int n0 = blockIdx.x * TN;
    const int b  = blockIdx.y;
    const bool fast = (n0 + 2 * TN <= T_);   // false only for last tile (n0=1984)

    // ---- shapelets bf16 + ss fp32 (inline; no precompute kernel) ----
    for (int i = tid; i < K_ * 16; i += NTH) {
        const int k = i >> 4, l4 = (i & 15) * 4;
        float4 v = *(const float4*)(shp + k * L_ + l4);
        ushort4 sv = { f2bf(v.x), f2bf(v.y), f2bf(v.z), f2bf(v.w) };
        *(ushort4*)&st[k][l4] = sv;
    }
    if (tid < K_) {
        float s = 0.f;
        for (int l = 0; l < L_; ++l) { float v = shp[tid * L_ + l]; s = fmaf(v, v, s); }
        ssb[tid] = s;
    }

    // ---- stage x as 4 shifted bf16 planes: j4 = 0..120 -> j coverage 0..123 ----
    const float* xb = x + ((size_t)b * M_) * T_ + n0;
    for (int g = tid; g < M_ * 31; g += NTH) {
        const int m = g / 31, j4 = (g - m * 31) * 4;     // j4 in {0,4,...,120}
        const float* src = xb + m * T_ + j4;
        float h[8];
        if (fast) {
            float4 v0 = *(const float4*)src;
            float4 v1 = *(const float4*)(src + 4);
            h[0] = v0.x; h[1] = v0.y; h[2] = v0.z; h[3] = v0.w;
            h[4] = v1.x; h[5] = v1.y; h[6] = v1.z; h[7] = v1.w;
        } else {
#pragma unroll
            for (int i = 0; i < 8; ++i)
                h[i] = (n0 + j4 + i < T_) ? src[i] : 0.f;
        }
        unsigned short hb[8];
#pragma unroll
        for (int i = 0; i < 8; ++i) hb[i] = f2bf(h[i]);
#pragma unroll
        for (int s = 0; s < 4; ++s) {
            ushort4 sv = { hb[s], hb[s + 1], hb[s + 2], hb[s + 3] };
            *(ushort4*)&xbuf4[m][s][j4] = sv;
        }
    }
    // ---- sqw fp32 sliding window: 8 threads per m, 8 n each (threads 0..127) ----
    if (tid < M_ * 8) {
        const int m = tid >> 3, j0 = (tid & 7) * 8;
        const float* xr = x + ((size_t)b * M_ + m) * T_ + n0;
        float s = 0.f;
        if (fast) {
#pragma unroll
            for (int qd = 0; qd < 16; ++qd) {
                float4 v = *(const float4*)(xr + j0 + qd * 4);
                s = fmaf(v.x, v.x, s); s = fmaf(v.y, v.y, s);
                s = fmaf(v.z, v.z, s); s = fmaf(v.w, v.w, s);
            }
            sqw[m][j0] = s;
#pragma unroll
            for (int d = 1; d < 8; ++d) {
                float a = xr[j0 + d + L_ - 1], r = xr[j0 + d - 1];
                s += a * a - r * r;
                sqw[m][j0 + d] = s;
            }
        } else {
            for (int l = 0; l < L_; ++l) {
                float v = (n0 + j0 + l < T_) ? xr[j0 + l] : 0.f;
                s = fmaf(v, v, s);
            }
            sqw[m][j0] = s;
            for (int d = 1; d < 8; ++d) {
                float a = (n0 + j0 + d + L_ - 1 < T_) ? xr[j0 + d + L_ - 1] : 0.f;
                float r = (n0 + j0 + d - 1 < T_) ? xr[j0 + d - 1] : 0.f;
                s += a * a - r * r;
                sqw[m][j0 + d] = s;
            }
        }
    }
    __syncthreads();

    // ---- per-lane MFMA coordinates (proven layout) ----
    const int lane = tid & 63;
    const int w  = tid >> 6;       // wave -> n-subtile [16w, 16w+16)
    const int rl = lane & 15;      // A-row (n within subtile) / B-col (k within tile)
    const int q  = lane >> 4;      // quad
    const int sp = rl & 3;                          // shift plane
    const int e0 = 16 * w + 8 * q + (rl & ~3);      // 4-aligned elem base (max 84)
    const int eq = e0 >> 2;                         // uint2 index (max 21; +9 fits)
    const int nrow = n0 + 16 * w + 4 * q;           // lane's 4 output rows: nrow + reg

    // b_frags (registers, whole kernel): st[16t+rl][8q+32h .. +7]
    bf16x8 bfr[2][2];
#pragma unroll
    for (int t = 0; t < 2; ++t)
#pragma unroll
        for (int h = 0; h < 2; ++h)
            bfr[t][h] = *(const bf16x8*)&st[16 * t + rl][8 * q + 32 * h];

    const float ssk0 = ssb[rl], ssk1 = ssb[16 + rl];

    const float* pr0 = pmap + (size_t)rl * (M_ * N_) + nrow;   // k = rl
    const float* pr1 = pr0 + (size_t)16 * M_ * N_;             // k = rl + 16

    f32x4 wd0 = (f32x4)0.f, wd1 = (f32x4)0.f;
    const f32x4 zero = (f32x4)0.f;

    // One m-step: MFMA from LDS planes + penalized accumulate with given pen regs.
    auto mstep = [&](int m, float4 pm0, float4 pm1) {
        const uint2* prow = (const uint2*)&xbuf4[m][sp][0];
        uint2 lo0 = prow[eq],     hi0 = prow[eq + 1];
        uint2 lo1 = prow[eq + 8], hi1 = prow[eq + 9];
        union { uint2 u2[2]; bf16x8 v; } fa0, fa1;
        fa0.u2[0] = lo0; fa0.u2[1] = hi0;
        fa1.u2[0] = lo1; fa1.u2[1] = hi1;

        f32x4 c0_ = __builtin_amdgcn_mfma_f32_16x16x32_bf16(fa0.v, bfr[0][0], zero, 0, 0, 0);
        c0_       = __builtin_amdgcn_mfma_f32_16x16x32_bf16(fa1.v, bfr[0][1], c0_, 0, 0, 0);
        f32x4 c1_ = __builtin_amdgcn_mfma_f32_16x16x32_bf16(fa0.v, bfr[1][0], zero, 0, 0, 0);
        c1_       = __builtin_amdgcn_mfma_f32_16x16x32_bf16(fa1.v, bfr[1][1], c1_, 0, 0, 0);

        const float pv0[4] = { pm0.x, pm0.y, pm0.z, pm0.w };
        const float pv1[4] = { pm1.x, pm1.y, pm1.z, pm1.w };
        f32x4 sq = *(const f32x4*)&sqw[m][16 * w + 4 * q];
#pragma unroll
        for (int r = 0; r < 4; ++r) {
            float pe0 = elu_pen(pv0[r]);
            float pe1 = elu_pen(pv1[r]);
            float u0 = fmaf(-2.f, c0_[r], sq[r] + ssk0);
            wd0[r] = fmaf(pe0, u0, wd0[r]);
            float u1 = fmaf(-2.f, c1_[r], sq[r] + ssk1);
            wd1[r] = fmaf(pe1, u1, wd1[r]);
        }
    };

    if (fast) {
        // Rolled m-pair loop with an explicit depth-2 rotating pen buffer.
        // Loads for pair mp+1 are issued BEFORE computing pair mp, so each load
        // has ~2 m-steps of MFMA/VALU (~300+ cy) to cover the ~200 cy L2 hit.
        // The loop stays ROLLED: register footprint is fixed (4 float4 in
        // flight), so no scratch spill regardless of scheduling (round-2 fix).
        float4 pa0 = *(const float4*)(pr0);
        float4 pa1 = *(const float4*)(pr1);
        float4 pb0 = *(const float4*)(pr0 + N_);
        float4 pb1 = *(const float4*)(pr1 + N_);
        for (int mp = 0; mp < M_ / 2; ++mp) {
            const int m = 2 * mp;
            float4 c0 = pa0, c1 = pa1, d0 = pb0, d1 = pb1;
            if (mp + 1 < M_ / 2) {
                const float* q0 = pr0 + (size_t)(m + 2) * N_;
                const float* q1 = pr1 + (size_t)(m + 2) * N_;
                pa0 = *(const float4*)(q0);
                pa1 = *(const float4*)(q1);
                pb0 = *(const float4*)(q0 + N_);
                pb1 = *(const float4*)(q1 + N_);
            }
            mstep(m, c0, c1);
            mstep(m + 1, d0, d1);
        }
    } else {
        // last n-tile only (32 of 2048 blocks): per-element guarded
        for (int m = 0; m < M_; ++m) {
            float4 pm0 = make_float4(0.f, 0.f, 0.f, 0.f);
            float4 pm1 = make_float4(0.f, 0.f, 0.f, 0.f);
            const float* r0_ = pr0 + (size_t)m * N_;
            const float* r1_ = pr1 + (size_t)m * N_;
            if (nrow     < N_) { pm0.x = r0_[0]; pm1.x = r1_[0]; }
            if (nrow + 1 < N_) { pm0.y = r0_[1]; pm1.y = r1_[1]; }
            if (nrow + 2 < N_) { pm0.z = r0_[2]; pm1.z = r1_[2]; }
            if (nrow + 3 < N_) { pm0.w = r0_[3]; pm1.w = r1_[3]; }
            mstep(m, pm0, pm1);
        }
    }

    // ---- min: 4 rows -> quads (shfl) -> LDS cross-wave -> 1 atomic per (b,k) ----
    __syncthreads();                       // sqw reads done; reuse as scratch
    float* red = (float*)&sqw[0][0];       // [4 waves][32]
#pragma unroll
    for (int t = 0; t < 2; ++t) {
        float lmin = __int_as_float(0x7F800000);
        const f32x4 wdv = t ? wd1 : wd0;
#pragma unroll
        for (int r = 0; r < 4; ++r)
            if (nrow + r < N_) lmin = fminf(lmin, wdv[r]);
        lmin = fminf(lmin, __shfl_xor(lmin, 16));
        lmin = fminf(lmin, __shfl_xor(lmin, 32));
        if (q == 0) red[w * 32 + t * 16 + rl] = lmin;
    }
    __syncthreads();
    if (tid < K_) {
        float v = fminf(fminf(red[tid], red[32 + tid]),
                        fminf(red[64 + tid], red[96 + tid]));
        atomicMin(out + (size_t)b * K_ + tid, __float_as_uint(fmaxf(v, 0.f)));
    }
}

extern "C" void kernel_launch(void* const* d_in, const int* in_sizes, int n_in,
                              void* d_out, int out_size, void* d_ws, size_t ws_size,
                              hipStream_t stream) {
    const float* x    = (const float*)d_in[0];   // (B, M, T)
    const float* shp  = (const float*)d_in[1];   // (K, L)
    const float* pmap = (const float*)d_in[2];   // (K, M, N)
    unsigned* out = (unsigned*)d_out;            // (B, K) float bits
    (void)d_ws; (void)ws_size;                   // no workspace: pen computed inline

    // out = 0xFFFFFFFF (> any non-negative float's bits) for atomicMin
    hipMemsetAsync(d_out, 0xFF, (size_t)B_ * K_ * sizeof(unsigned), stream);

    dim3 grid((N_ + TN - 1) / TN, B_);           // 32 x 64 = 2048 blocks
    shapelet_mfma_kernel<<<grid, dim3(NTH), 0, stream>>>(x, shp, pmap, out);
}